// Round 3
// baseline (348.375 us; speedup 1.0000x reference)
//
#include <hip/hip_runtime.h>

#define BB 64
#define AA 8732
#define GG 50
#define CC 81
#define NEG_RATIO 3
#define HW 16          // waves per k_hardneg block
#define HSTRIDE 257    // padded per-wave histogram stride
#define NCHUNK 137     // ceil(AA/64)
#define XB 27          // k_match blocks per batch (137 = 27*5+2 -> near-perfect balance)

// ws layout (float offsets):
//   acc_slots[2048] @0            (float, one per k_match block; XB*BB=1728 used)
//   np_slots[2048]  @2048         (int,   one per k_match block)
//   per_b[64]       @4096         (float, per-batch total)
//   den_b[64]       @4160         (int,   per-batch denominator)
//   ctr             @4224         (unsigned, last-block-done counter; zeroed by k_match)
//   conf_neg        @8192         (BB*AA floats)

__device__ __forceinline__ unsigned mono_key(float f) {
    unsigned u = __float_as_uint(f);
    u = (u & 0x80000000u) ? ~u : (u | 0x80000000u);  // ascending float -> ascending uint
    return ~u;                                        // ascending key == descending float
}

// exact inverse of mono_key (bijection) -> recover conf value from key, bit-identical
__device__ __forceinline__ float unkey_val(unsigned key) {
    unsigned u = ~key;
    return __uint_as_float((u & 0x80000000u) ? (u & 0x7fffffffu) : ~u);
}

// Grid-stride, software-pipelined, atomic-free main pass.
// Key structure change vs prior round: scores are folded to a per-lane partial
// expsum the moment their loads land (end of previous iteration), so only ONE
// float of softmax state is carried instead of 20 score registers. The fold uses
// the exact same FP association/order as before -> bit-identical results.
__global__ __launch_bounds__(256, 5) void k_match(
    const float* __restrict__ pred_boxes, const float* __restrict__ pred_scores,
    const float* __restrict__ gt_boxes, const int* __restrict__ gt_labels,
    float* __restrict__ confneg_out,
    float* __restrict__ acc_slots, int* __restrict__ np_slots,
    unsigned* __restrict__ ctr)
{
    __shared__ float4 sgt[GG];
    __shared__ float  sarea[GG];
    __shared__ int    slab[GG];
    __shared__ float  redf[4];
    __shared__ int    redi[4];

    const int tid = threadIdx.x;
    const int b = blockIdx.y;
    const int x = blockIdx.x;          // 0..XB-1
    const int grp = tid >> 2;          // anchor-in-chunk
    const int q   = tid & 3;           // lane within 4-lane group

    // zero the fused-final counter for this iteration (visible to k_hardneg via stream order)
    if (b == 0 && x == 0 && tid == 0) *ctr = 0u;

    if (tid < GG) {
        float4 g4 = ((const float4*)gt_boxes)[b * GG + tid];
        sgt[tid] = g4;
        sarea[tid] = (g4.z - g4.x) * (g4.w - g4.y);
        slab[tid] = gt_labels[b * GG + tid];
    }
    __syncthreads();   // once per block (~5 chunks)

    const float*  sb = pred_scores + (size_t)b * AA * CC;
    const float4* bbx = (const float4*)pred_boxes + (size_t)b * AA;

    float contrib = 0.f;
    int npos = 0;

    // ---- prologue: chunk x's box + scores -> partial expsum ----
    const int a0 = x * 64 + grp;                 // x<=26 -> always < AA
    float4 cbox = bbx[a0];
    const float* crow = sb + (size_t)a0 * CC;
    float psum;
    {
        const float4 v0 = *(const float4*)(crow + 4 * q);
        const float4 v1 = *(const float4*)(crow + 4 * q + 16);
        const float4 v2 = *(const float4*)(crow + 4 * q + 32);
        const float4 v3 = *(const float4*)(crow + 4 * q + 48);
        const float4 v4 = *(const float4*)(crow + 4 * q + 64);
        const float  v80 = crow[80];
        float ps = 0.f;
        ps += __expf(v0.x) + __expf(v0.y) + __expf(v0.z) + __expf(v0.w);
        ps += __expf(v1.x) + __expf(v1.y) + __expf(v1.z) + __expf(v1.w);
        ps += __expf(v2.x) + __expf(v2.y) + __expf(v2.z) + __expf(v2.w);
        ps += __expf(v3.x) + __expf(v3.y) + __expf(v3.z) + __expf(v3.w);
        ps += __expf(v4.x) + __expf(v4.y) + __expf(v4.z) + __expf(v4.w);
        if (q == 0) ps += __expf(v80);
        psum = ps;
    }

    for (int c = x; c < NCHUNK; c += XB) {
        const int a = c * 64 + grp;
        const bool valid = a < AA;

        // ---- prefetch next chunk (clamped; loads in flight during IoU) ----
        int cnx = c + XB; if (cnx >= NCHUNK) cnx = c;
        int an = cnx * 64 + grp; if (an >= AA) an = AA - 1;
        const float4 nbox = bbx[an];
        const float* nrow = sb + (size_t)an * CC;
        const float4 n0 = *(const float4*)(nrow + 4 * q);
        const float4 n1 = *(const float4*)(nrow + 4 * q + 16);
        const float4 n2 = *(const float4*)(nrow + 4 * q + 32);
        const float4 n3 = *(const float4*)(nrow + 4 * q + 48);
        const float4 n4 = *(const float4*)(nrow + 4 * q + 64);
        const float  n80 = nrow[80];

        // ---- IoU argmax, 4-way split, fixed trip count (fully unrolled) ----
        const float4 pb = cbox;
        const float area_p = (pb.z - pb.x) * (pb.w - pb.y);
        float best = -1.f; int bidx = 0x7fffffff;
        #pragma unroll
        for (int i = 0; i < 13; ++i) {
            const int g = q + (i << 2);
            const bool gv = g < GG;          // q>=2, i==12 -> masked off
            const int gc = gv ? g : 0;       // clamped broadcast read
            const float4 gb = sgt[gc];
            const float  sa = sarea[gc];
            float iw = fmaxf(fminf(pb.z, gb.z) - fmaxf(pb.x, gb.x), 0.f);
            float ih = fmaxf(fminf(pb.w, gb.w) - fmaxf(pb.y, gb.y), 0.f);
            float inter = iw * ih;
            float uni = fmaxf(area_p + sa - inter, 1e-6f);
            float iou = __fdividef(inter, uni);
            if (gv && iou > best) { best = iou; bidx = g; }   // strict > keeps FIRST max in-lane
        }
        #pragma unroll
        for (int off = 1; off < 4; off <<= 1) {         // first-max merge: equal -> smaller idx
            float ov = __shfl_xor(best, off);
            int   oi = __shfl_xor(bidx, off);
            if (ov > best || (ov == best && oi < bidx)) { best = ov; bidx = oi; }
        }
        const int label = (best > 0.5f) ? slab[bidx] : 0;   // uniform across group

        // issue label-score load early (L2 hit), used after the shuffle reduce
        const float labv = crow[label];

        // ---- current softmax denominator from the carried partial ----
        float sm = psum;
        sm += __shfl_xor(sm, 1);
        sm += __shfl_xor(sm, 2);

        if (q == 0 && valid) {
            const float conf = __logf(sm) - labv;    // scores ~N(0,1): no max-shift needed
            const size_t ai = (size_t)b * AA + a;
            const bool pm = label > 0;
            confneg_out[ai] = pm ? -1.f : conf;
            if (pm) {
                npos++;
                const float4 gb = sgt[bidx];
                float sl1 = 0.f, d, ad;
                d = pb.x - gb.x; ad = fabsf(d); sl1 += (ad < 1.f) ? 0.5f * d * d : ad - 0.5f;
                d = pb.y - gb.y; ad = fabsf(d); sl1 += (ad < 1.f) ? 0.5f * d * d : ad - 0.5f;
                d = pb.z - gb.z; ad = fabsf(d); sl1 += (ad < 1.f) ? 0.5f * d * d : ad - 0.5f;
                d = pb.w - gb.w; ad = fabsf(d); sl1 += (ad < 1.f) ? 0.5f * d * d : ad - 0.5f;
                contrib += sl1 + conf;
            }
        }

        // ---- fold next chunk's scores to a partial expsum (score regs die here;
        // identical association/order as the original softmax -> bit-exact) ----
        float ps = 0.f;
        ps += __expf(n0.x) + __expf(n0.y) + __expf(n0.z) + __expf(n0.w);
        ps += __expf(n1.x) + __expf(n1.y) + __expf(n1.z) + __expf(n1.w);
        ps += __expf(n2.x) + __expf(n2.y) + __expf(n2.z) + __expf(n2.w);
        ps += __expf(n3.x) + __expf(n3.y) + __expf(n3.z) + __expf(n3.w);
        ps += __expf(n4.x) + __expf(n4.y) + __expf(n4.z) + __expf(n4.w);
        if (q == 0) ps += __expf(n80);

        // rotate
        cbox = nbox; crow = nrow; psum = ps;
    }

    // ---- block reduction -> per-block slot (no atomics) ----
    #pragma unroll
    for (int off = 32; off; off >>= 1) {
        contrib += __shfl_down(contrib, off);
        npos    += __shfl_down(npos, off);
    }
    const int wv = tid >> 6;
    if ((tid & 63) == 0) { redf[wv] = contrib; redi[wv] = npos; }
    __syncthreads();
    if (tid == 0) {
        acc_slots[b * XB + x] = redf[0] + redf[1] + redf[2] + redf[3];
        np_slots[b * XB + x]  = redi[0] + redi[1] + redi[2] + redi[3];
    }
}

// Radix-256 k-th selection + hard-negative sum + fused final reduction.
// Values of selected elements decode bit-exactly from their keys (mono_key is a
// bijection, and all selected hard-negs are negatives: conf >= 0 > -1, k <= 3*np << #neg),
// so the conf array is gone entirely.
__global__ __launch_bounds__(1024) void k_hardneg(
    const float* __restrict__ confneg,
    const int* __restrict__ np_slots, const float* __restrict__ acc_slots,
    float* __restrict__ per_b, int* __restrict__ den_b,
    unsigned* __restrict__ ctr, float* __restrict__ out)
{
    __shared__ unsigned hist[HW * HSTRIDE];   // per-wave privatized
    __shared__ unsigned binsum[256];
    __shared__ unsigned sel[2];
    __shared__ unsigned uE[HW], uG[HW], eb[HW];
    __shared__ float    fred[HW];
    __shared__ int      stot;
    __shared__ int      slast;

    const int b = blockIdx.x;
    const int tid = threadIdx.x;
    const int wv = tid >> 6;
    const int lane = tid & 63;

    int np = 0;
    #pragma unroll
    for (int i = 0; i < XB; ++i) np += np_slots[b * XB + i];
    int k = NEG_RATIO * np; if (k > AA - 1) k = AA - 1;

    float hn = 0.f;                 // per-batch hard-negative sum (tid 0 only)
    if (k > 0) {                    // k uniform across block: barriers inside are safe
        const float* cn = confneg + (size_t)b * AA;

        // contiguous per-thread chunks preserve stable-by-index tie semantics
        const int lo = tid * 9;
        int nk = AA - lo; nk = nk > 9 ? 9 : (nk < 0 ? 0 : nk);
        unsigned keys[9];
        #pragma unroll
        for (int j = 0; j < 9; ++j)
            if (j < nk) keys[j] = mono_key(cn[lo + j]);

        // ---- 4-level radix-256 select of k-th smallest key ----
        unsigned prefix = 0, kk = (unsigned)k;
        for (int lev = 0; lev < 4; ++lev) {
            const int shift = 24 - 8 * lev;
            for (int i = tid; i < HW * HSTRIDE; i += 1024) hist[i] = 0;
            __syncthreads();
            #pragma unroll
            for (int j = 0; j < 9; ++j) {
                if (j < nk) {
                    const unsigned key = keys[j];
                    if (lev == 0 || (key >> (shift + 8)) == prefix)
                        atomicAdd(&hist[wv * HSTRIDE + ((key >> shift) & 255u)], 1u);
                }
            }
            __syncthreads();
            if (tid < 256) {
                unsigned s = 0;
                #pragma unroll
                for (int w = 0; w < HW; ++w) s += hist[w * HSTRIDE + tid];
                binsum[tid] = s;
            }
            __syncthreads();
            if (wv == 0) {   // wave 0 scans 256 bins: 4 bins/lane + shfl scan
                const unsigned v0 = binsum[4 * lane], v1 = binsum[4 * lane + 1];
                const unsigned v2 = binsum[4 * lane + 2], v3 = binsum[4 * lane + 3];
                const unsigned lsum = v0 + v1 + v2 + v3;
                unsigned sc = lsum;
                #pragma unroll
                for (int off = 1; off < 64; off <<= 1) {
                    unsigned t = __shfl_up(sc, off);
                    if (lane >= off) sc += t;
                }
                const unsigned excl = sc - lsum;
                if (kk > excl && kk <= sc) {
                    unsigned cacc = excl;
                    if (kk <= cacc + v0)              { sel[0] = 4 * lane;     sel[1] = kk - cacc; }
                    else if (kk <= (cacc += v0) + v1) { sel[0] = 4 * lane + 1; sel[1] = kk - cacc; }
                    else if (kk <= (cacc += v1) + v2) { sel[0] = 4 * lane + 2; sel[1] = kk - cacc; }
                    else                              { sel[0] = 4 * lane + 3; sel[1] = kk - cacc - v2; }
                }
            }
            __syncthreads();
            prefix = (prefix << 8) | sel[0];
            kk = sel[1];
        }
        const unsigned kth = prefix;

        // ---- stable selection sum: key<kth all in; ==kth by ascending index ----
        int cntG = 0, cntE = 0; float sum_gt = 0.f;
        #pragma unroll
        for (int j = 0; j < 9; ++j) {
            if (j < nk) {
                if (keys[j] < kth)       { cntG++; sum_gt += unkey_val(keys[j]); }
                else if (keys[j] == kth) { cntE++; }
            }
        }
        int sc = cntE;
        #pragma unroll
        for (int off = 1; off < 64; off <<= 1) {
            int t = __shfl_up(sc, off);
            if (lane >= off) sc += t;
        }
        int gt = cntG;
        #pragma unroll
        for (int off = 32; off; off >>= 1) gt += __shfl_down(gt, off);
        if (lane == 63) uE[wv] = (unsigned)sc;
        if (lane == 0)  uG[wv] = (unsigned)gt;
        __syncthreads();
        if (wv == 0) {
            unsigned e = (lane < HW) ? uE[lane] : 0u;
            unsigned g = (lane < HW) ? uG[lane] : 0u;
            unsigned se = e;
            #pragma unroll
            for (int off = 1; off < 16; off <<= 1) {
                unsigned t = __shfl_up(se, off);
                if (lane >= off) se += t;
            }
            if (lane < HW) eb[lane] = se - e;
            #pragma unroll
            for (int off = 8; off; off >>= 1) g += __shfl_down(g, off);
            if (lane == 0) stot = (int)g;
        }
        __syncthreads();
        const int m = k - stot;                 // #ties to include, lowest indices first
        const int exclE = (int)eb[wv] + (sc - cntE);

        float sum_eq = 0.f;
        if (m > 0 && cntE > 0) {
            int seen = 0;
            #pragma unroll
            for (int j = 0; j < 9; ++j) {
                if (j < nk && keys[j] == kth) {
                    if (exclE + seen < m) sum_eq += unkey_val(keys[j]);
                    seen++;
                }
            }
        }

        float contrib = sum_gt + sum_eq;
        #pragma unroll
        for (int off = 32; off; off >>= 1) contrib += __shfl_down(contrib, off);
        if (lane == 0) fred[wv] = contrib;
        __syncthreads();
        if (tid == 0) {
            #pragma unroll
            for (int w = 0; w < HW; ++w) hn += fred[w];
        }
    }

    // ---- fused final reduction (replaces k_final): last block to finish sums all b.
    // Cross-XCD safety: per-batch results written AND read with device-scope atomics;
    // release = threadfence + ctr atomicAdd, ctr zeroed by k_match (stream order). ----
    if (tid == 0) {
        float accb = 0.f;
        #pragma unroll
        for (int i = 0; i < XB; ++i) accb += acc_slots[b * XB + i];
        atomicExch(&per_b[b], accb + hn);
        atomicExch(&den_b[b], np > 1 ? np : 1);
        __threadfence();
        unsigned prev = atomicAdd(ctr, 1u);
        slast = (prev == (unsigned)(BB - 1)) ? 1 : 0;
    }
    __syncthreads();
    if (slast && tid < BB) {
        float v = atomicAdd(&per_b[tid], 0.f);   // coherent read
        int   d = atomicAdd(&den_b[tid], 0);
        #pragma unroll
        for (int off = 32; off; off >>= 1) {
            v += __shfl_down(v, off);
            d += __shfl_down(d, off);
        }
        if (tid == 0) out[0] = v / (float)d;
    }
}

extern "C" void kernel_launch(void* const* d_in, const int* in_sizes, int n_in,
                              void* d_out, int out_size, void* d_ws, size_t ws_size,
                              hipStream_t stream) {
    const float* pred_boxes  = (const float*)d_in[0];
    const float* pred_scores = (const float*)d_in[1];
    const float* gt_boxes    = (const float*)d_in[2];
    const int*   gt_labels   = (const int*)d_in[3];

    float*    ws        = (float*)d_ws;
    float*    acc_slots = ws;                     // 2048 floats (1728 used)
    int*      np_slots  = (int*)(ws + 2048);      // 2048 ints  (1728 used)
    float*    per_b     = ws + 4096;              // 64 floats
    int*      den_b     = (int*)(ws + 4160);      // 64 ints
    unsigned* ctr       = (unsigned*)(ws + 4224); // 1 unsigned (zeroed by k_match)
    float*    conf_neg  = ws + 8192;              // BB*AA floats

    // no memset needed: every ws word read is written by a kernel first
    dim3 g1(XB, BB);   // 27 x 64 blocks, grid-stride over 137 chunks of 64 anchors
    k_match<<<g1, 256, 0, stream>>>(pred_boxes, pred_scores, gt_boxes, gt_labels,
                                    conf_neg, acc_slots, np_slots, ctr);
    k_hardneg<<<BB, 1024, 0, stream>>>(conf_neg, np_slots, acc_slots,
                                       per_b, den_b, ctr, (float*)d_out);
}

// Round 4
// 300.433 us; speedup vs baseline: 1.1596x; 1.1596x over previous
//
#include <hip/hip_runtime.h>

#define BB 64
#define AA 8732
#define GG 50
#define CC 81
#define NEG_RATIO 3
#define HW 16          // waves per k_hardneg block
#define HSTRIDE 257    // padded per-wave histogram stride
#define NCHUNK 137     // ceil(AA/64)
#define XB 16          // k_match blocks per batch

// ws layout (float offsets):
//   acc_slots[1024] @0            (float, one per k_match block)
//   np_slots[1024]  @1024         (int,   one per k_match block)
//   per_b[64]       @2048         (float, per-batch total)
//   den_b[64]       @2112         (int,   per-batch denominator)
//   ctr             @2176         (unsigned, last-block-done counter; zeroed by k_match)
//   conf_neg        @4096         (BB*AA floats)

__device__ __forceinline__ unsigned mono_key(float f) {
    unsigned u = __float_as_uint(f);
    u = (u & 0x80000000u) ? ~u : (u | 0x80000000u);  // ascending float -> ascending uint
    return ~u;                                        // ascending key == descending float
}

// exact inverse of mono_key (bijection) -> recover conf value from key, bit-identical
__device__ __forceinline__ float unkey_val(unsigned key) {
    unsigned u = ~key;
    return __uint_as_float((u & 0x80000000u) ? (u & 0x7fffffffu) : ~u);
}

// Grid-stride, software-pipelined, atomic-free main pass.
// NOTE (round-3 post-mortem): the 20 prefetched score registers held live across
// the IoU phase ARE the software pipeline — attempts to shrink them (carried
// expsum fold, launch_bounds 5) let the compiler sink the loads to their uses
// and regressed 3x. Keep VGPR=104 / 4 waves/SIMD.
__global__ __launch_bounds__(256, 4) void k_match(
    const float* __restrict__ pred_boxes, const float* __restrict__ pred_scores,
    const float* __restrict__ gt_boxes, const int* __restrict__ gt_labels,
    float* __restrict__ confneg_out,
    float* __restrict__ acc_slots, int* __restrict__ np_slots,
    unsigned* __restrict__ ctr)
{
    __shared__ float4 sgt[GG];
    __shared__ float  sarea[GG];
    __shared__ int    slab[GG];
    __shared__ float  redf[4];
    __shared__ int    redi[4];

    const int tid = threadIdx.x;
    const int b = blockIdx.y;
    const int x = blockIdx.x;          // 0..XB-1
    const int grp = tid >> 2;          // anchor-in-chunk
    const int q   = tid & 3;           // lane within 4-lane group

    // zero the fused-final counter for this iteration (visible to k_hardneg via stream order)
    if (b == 0 && x == 0 && tid == 0) *ctr = 0u;

    if (tid < GG) {
        float4 g4 = ((const float4*)gt_boxes)[b * GG + tid];
        sgt[tid] = g4;
        sarea[tid] = (g4.z - g4.x) * (g4.w - g4.y);
        slab[tid] = gt_labels[b * GG + tid];
    }
    __syncthreads();   // once per block (~9 chunks)

    const float*  sb = pred_scores + (size_t)b * AA * CC;
    const float4* bbx = (const float4*)pred_boxes + (size_t)b * AA;

    float contrib = 0.f;
    int npos = 0;

    // ---- prefetch first chunk ----
    int a0 = x * 64 + grp;
    int am = a0 < AA ? a0 : AA - 1;
    float4 nbox = bbx[am];
    const float* nrow = sb + (size_t)am * CC;
    float4 ns0 = *(const float4*)(nrow + 4 * q);
    float4 ns1 = *(const float4*)(nrow + 4 * q + 16);
    float4 ns2 = *(const float4*)(nrow + 4 * q + 32);
    float4 ns3 = *(const float4*)(nrow + 4 * q + 48);
    float4 ns4 = *(const float4*)(nrow + 4 * q + 64);
    float  ns80 = nrow[80];

    for (int c = x; c < NCHUNK; c += XB) {
        // rotate prefetched regs into current
        const float4 pb = nbox;
        const float4 s0 = ns0, s1 = ns1, s2 = ns2, s3 = ns3, s4 = ns4;
        const float  s80 = ns80;
        const float* crow = nrow;      // current row base (for label-score load)
        const int a = c * 64 + grp;
        const bool valid = a < AA;

        // prefetch next chunk (clamped; unconditional -> no spill-prone masks)
        int cnx = c + XB; if (cnx >= NCHUNK) cnx = c;
        int an = cnx * 64 + grp; if (an >= AA) an = AA - 1;
        nbox = bbx[an];
        nrow = sb + (size_t)an * CC;
        ns0 = *(const float4*)(nrow + 4 * q);
        ns1 = *(const float4*)(nrow + 4 * q + 16);
        ns2 = *(const float4*)(nrow + 4 * q + 32);
        ns3 = *(const float4*)(nrow + 4 * q + 48);
        ns4 = *(const float4*)(nrow + 4 * q + 64);
        ns80 = nrow[80];

        // ---- IoU argmax, 4-way split; FIXED trip count so the compiler can
        // fully unroll and batch the 26 LDS reads ----
        const float area_p = (pb.z - pb.x) * (pb.w - pb.y);
        float best = -1.f; int bidx = 0x7fffffff;
        #pragma unroll
        for (int i = 0; i < 13; ++i) {
            const int g = q + (i << 2);
            const bool gv = g < GG;          // q>=2, i==12 -> masked off
            const int gc = gv ? g : 0;       // clamped broadcast read
            const float4 gb = sgt[gc];
            const float  sa = sarea[gc];
            float iw = fmaxf(fminf(pb.z, gb.z) - fmaxf(pb.x, gb.x), 0.f);
            float ih = fmaxf(fminf(pb.w, gb.w) - fmaxf(pb.y, gb.y), 0.f);
            float inter = iw * ih;
            float uni = fmaxf(area_p + sa - inter, 1e-6f);
            float iou = __fdividef(inter, uni);
            if (gv && iou > best) { best = iou; bidx = g; }   // strict > keeps FIRST max in-lane
        }
        #pragma unroll
        for (int off = 1; off < 4; off <<= 1) {         // first-max merge: equal -> smaller idx
            float ov = __shfl_xor(best, off);
            int   oi = __shfl_xor(bidx, off);
            if (ov > best || (ov == best && oi < bidx)) { best = ov; bidx = oi; }
        }
        const int label = (best > 0.5f) ? slab[bidx] : 0;   // uniform across group

        // ---- softmax denominator over 81 scores (lane q owns float4s f=q+4t);
        // label score fetched directly (L2 hit) instead of an in-register select chain ----
        float sm = 0.f;
        sm += __expf(s0.x) + __expf(s0.y) + __expf(s0.z) + __expf(s0.w);
        sm += __expf(s1.x) + __expf(s1.y) + __expf(s1.z) + __expf(s1.w);
        sm += __expf(s2.x) + __expf(s2.y) + __expf(s2.z) + __expf(s2.w);
        sm += __expf(s3.x) + __expf(s3.y) + __expf(s3.z) + __expf(s3.w);
        sm += __expf(s4.x) + __expf(s4.y) + __expf(s4.z) + __expf(s4.w);
        if (q == 0) sm += __expf(s80);
        sm += __shfl_xor(sm, 1);
        sm += __shfl_xor(sm, 2);

        if (q == 0 && valid) {
            const float labv = crow[label];          // bit-identical to in-register select
            const float conf = __logf(sm) - labv;    // scores ~N(0,1): no max-shift needed
            const size_t ai = (size_t)b * AA + a;
            const bool pm = label > 0;
            confneg_out[ai] = pm ? -1.f : conf;
            if (pm) {
                npos++;
                const float4 gb = sgt[bidx];
                float sl1 = 0.f, d, ad;
                d = pb.x - gb.x; ad = fabsf(d); sl1 += (ad < 1.f) ? 0.5f * d * d : ad - 0.5f;
                d = pb.y - gb.y; ad = fabsf(d); sl1 += (ad < 1.f) ? 0.5f * d * d : ad - 0.5f;
                d = pb.z - gb.z; ad = fabsf(d); sl1 += (ad < 1.f) ? 0.5f * d * d : ad - 0.5f;
                d = pb.w - gb.w; ad = fabsf(d); sl1 += (ad < 1.f) ? 0.5f * d * d : ad - 0.5f;
                contrib += sl1 + conf;
            }
        }
    }

    // ---- block reduction -> per-block slot (no atomics) ----
    #pragma unroll
    for (int off = 32; off; off >>= 1) {
        contrib += __shfl_down(contrib, off);
        npos    += __shfl_down(npos, off);
    }
    const int wv = tid >> 6;
    if ((tid & 63) == 0) { redf[wv] = contrib; redi[wv] = npos; }
    __syncthreads();
    if (tid == 0) {
        acc_slots[b * XB + x] = redf[0] + redf[1] + redf[2] + redf[3];
        np_slots[b * XB + x]  = redi[0] + redi[1] + redi[2] + redi[3];
    }
}

// Radix-256 k-th selection + hard-negative sum + fused final reduction.
// Values of selected elements decode bit-exactly from their keys (mono_key is a
// bijection, and all selected hard-negs are negatives: conf >= 0 > -1, k <= 3*np << #neg),
// so the conf array is gone entirely.
__global__ __launch_bounds__(1024) void k_hardneg(
    const float* __restrict__ confneg,
    const int* __restrict__ np_slots, const float* __restrict__ acc_slots,
    float* __restrict__ per_b, int* __restrict__ den_b,
    unsigned* __restrict__ ctr, float* __restrict__ out)
{
    __shared__ unsigned hist[HW * HSTRIDE];   // per-wave privatized
    __shared__ unsigned binsum[256];
    __shared__ unsigned sel[2];
    __shared__ unsigned uE[HW], uG[HW], eb[HW];
    __shared__ float    fred[HW];
    __shared__ int      stot;
    __shared__ int      slast;

    const int b = blockIdx.x;
    const int tid = threadIdx.x;
    const int wv = tid >> 6;
    const int lane = tid & 63;

    int np = 0;
    #pragma unroll
    for (int i = 0; i < XB; ++i) np += np_slots[b * XB + i];
    int k = NEG_RATIO * np; if (k > AA - 1) k = AA - 1;

    float hn = 0.f;                 // per-batch hard-negative sum (tid 0 only)
    if (k > 0) {                    // k uniform across block: barriers inside are safe
        const float* cn = confneg + (size_t)b * AA;

        // contiguous per-thread chunks preserve stable-by-index tie semantics
        const int lo = tid * 9;
        int nk = AA - lo; nk = nk > 9 ? 9 : (nk < 0 ? 0 : nk);
        unsigned keys[9];
        #pragma unroll
        for (int j = 0; j < 9; ++j)
            if (j < nk) keys[j] = mono_key(cn[lo + j]);

        // ---- 4-level radix-256 select of k-th smallest key ----
        unsigned prefix = 0, kk = (unsigned)k;
        for (int lev = 0; lev < 4; ++lev) {
            const int shift = 24 - 8 * lev;
            for (int i = tid; i < HW * HSTRIDE; i += 1024) hist[i] = 0;
            __syncthreads();
            #pragma unroll
            for (int j = 0; j < 9; ++j) {
                if (j < nk) {
                    const unsigned key = keys[j];
                    if (lev == 0 || (key >> (shift + 8)) == prefix)
                        atomicAdd(&hist[wv * HSTRIDE + ((key >> shift) & 255u)], 1u);
                }
            }
            __syncthreads();
            if (tid < 256) {
                unsigned s = 0;
                #pragma unroll
                for (int w = 0; w < HW; ++w) s += hist[w * HSTRIDE + tid];
                binsum[tid] = s;
            }
            __syncthreads();
            if (wv == 0) {   // wave 0 scans 256 bins: 4 bins/lane + shfl scan
                const unsigned v0 = binsum[4 * lane], v1 = binsum[4 * lane + 1];
                const unsigned v2 = binsum[4 * lane + 2], v3 = binsum[4 * lane + 3];
                const unsigned lsum = v0 + v1 + v2 + v3;
                unsigned sc = lsum;
                #pragma unroll
                for (int off = 1; off < 64; off <<= 1) {
                    unsigned t = __shfl_up(sc, off);
                    if (lane >= off) sc += t;
                }
                const unsigned excl = sc - lsum;
                if (kk > excl && kk <= sc) {
                    unsigned cacc = excl;
                    if (kk <= cacc + v0)              { sel[0] = 4 * lane;     sel[1] = kk - cacc; }
                    else if (kk <= (cacc += v0) + v1) { sel[0] = 4 * lane + 1; sel[1] = kk - cacc; }
                    else if (kk <= (cacc += v1) + v2) { sel[0] = 4 * lane + 2; sel[1] = kk - cacc; }
                    else                              { sel[0] = 4 * lane + 3; sel[1] = kk - cacc - v2; }
                }
            }
            __syncthreads();
            prefix = (prefix << 8) | sel[0];
            kk = sel[1];
        }
        const unsigned kth = prefix;

        // ---- stable selection sum: key<kth all in; ==kth by ascending index ----
        int cntG = 0, cntE = 0; float sum_gt = 0.f;
        #pragma unroll
        for (int j = 0; j < 9; ++j) {
            if (j < nk) {
                if (keys[j] < kth)       { cntG++; sum_gt += unkey_val(keys[j]); }
                else if (keys[j] == kth) { cntE++; }
            }
        }
        int sc = cntE;
        #pragma unroll
        for (int off = 1; off < 64; off <<= 1) {
            int t = __shfl_up(sc, off);
            if (lane >= off) sc += t;
        }
        int gt = cntG;
        #pragma unroll
        for (int off = 32; off; off >>= 1) gt += __shfl_down(gt, off);
        if (lane == 63) uE[wv] = (unsigned)sc;
        if (lane == 0)  uG[wv] = (unsigned)gt;
        __syncthreads();
        if (wv == 0) {
            unsigned e = (lane < HW) ? uE[lane] : 0u;
            unsigned g = (lane < HW) ? uG[lane] : 0u;
            unsigned se = e;
            #pragma unroll
            for (int off = 1; off < 16; off <<= 1) {
                unsigned t = __shfl_up(se, off);
                if (lane >= off) se += t;
            }
            if (lane < HW) eb[lane] = se - e;
            #pragma unroll
            for (int off = 8; off; off >>= 1) g += __shfl_down(g, off);
            if (lane == 0) stot = (int)g;
        }
        __syncthreads();
        const int m = k - stot;                 // #ties to include, lowest indices first
        const int exclE = (int)eb[wv] + (sc - cntE);

        float sum_eq = 0.f;
        if (m > 0 && cntE > 0) {
            int seen = 0;
            #pragma unroll
            for (int j = 0; j < 9; ++j) {
                if (j < nk && keys[j] == kth) {
                    if (exclE + seen < m) sum_eq += unkey_val(keys[j]);
                    seen++;
                }
            }
        }

        float contrib = sum_gt + sum_eq;
        #pragma unroll
        for (int off = 32; off; off >>= 1) contrib += __shfl_down(contrib, off);
        if (lane == 0) fred[wv] = contrib;
        __syncthreads();
        if (tid == 0) {
            #pragma unroll
            for (int w = 0; w < HW; ++w) hn += fred[w];
        }
    }

    // ---- fused final reduction (replaces k_final): last block to finish sums all b.
    // Cross-XCD safety: per-batch results written AND read with device-scope atomics;
    // release = threadfence + ctr atomicAdd, ctr zeroed by k_match (stream order). ----
    if (tid == 0) {
        float accb = 0.f;
        #pragma unroll
        for (int i = 0; i < XB; ++i) accb += acc_slots[b * XB + i];
        atomicExch(&per_b[b], accb + hn);
        atomicExch(&den_b[b], np > 1 ? np : 1);
        __threadfence();
        unsigned prev = atomicAdd(ctr, 1u);
        slast = (prev == (unsigned)(BB - 1)) ? 1 : 0;
    }
    __syncthreads();
    if (slast && tid < BB) {
        float v = atomicAdd(&per_b[tid], 0.f);   // coherent read
        int   d = atomicAdd(&den_b[tid], 0);
        #pragma unroll
        for (int off = 32; off; off >>= 1) {
            v += __shfl_down(v, off);
            d += __shfl_down(d, off);
        }
        if (tid == 0) out[0] = v / (float)d;
    }
}

extern "C" void kernel_launch(void* const* d_in, const int* in_sizes, int n_in,
                              void* d_out, int out_size, void* d_ws, size_t ws_size,
                              hipStream_t stream) {
    const float* pred_boxes  = (const float*)d_in[0];
    const float* pred_scores = (const float*)d_in[1];
    const float* gt_boxes    = (const float*)d_in[2];
    const int*   gt_labels   = (const int*)d_in[3];

    float*    ws        = (float*)d_ws;
    float*    acc_slots = ws;                     // 1024 floats
    int*      np_slots  = (int*)(ws + 1024);      // 1024 ints
    float*    per_b     = ws + 2048;              // 64 floats
    int*      den_b     = (int*)(ws + 2112);      // 64 ints
    unsigned* ctr       = (unsigned*)(ws + 2176); // 1 unsigned (zeroed by k_match)
    float*    conf_neg  = ws + 4096;              // BB*AA floats

    // no memset needed: every ws word read is written by a kernel first
    dim3 g1(XB, BB);   // 16 x 64 blocks, grid-stride over 137 chunks of 64 anchors
    k_match<<<g1, 256, 0, stream>>>(pred_boxes, pred_scores, gt_boxes, gt_labels,
                                    conf_neg, acc_slots, np_slots, ctr);
    k_hardneg<<<BB, 1024, 0, stream>>>(conf_neg, np_slots, acc_slots,
                                       per_b, den_b, ctr, (float*)d_out);
}